// Round 1
// baseline (4704.998 us; speedup 1.0000x reference)
//
#include <hip/hip_runtime.h>
#include <math.h>

#define EPSF 1e-8f
#define LAM 20.0f

// ---------------------------------------------------------------------------
// Kernel 1: row L2 norms. im: 8192 rows x 512, s: 4096 rows x 512.
// 4 rows per 256-thread block (one wave per row).
// ---------------------------------------------------------------------------
__global__ __launch_bounds__(256) void row_norms(const float* __restrict__ im,
                                                 const float* __restrict__ s,
                                                 float* __restrict__ nim,
                                                 float* __restrict__ ns) {
  int row = blockIdx.x * 4 + (threadIdx.x >> 6);
  int lane = threadIdx.x & 63;
  const float* src;
  float* dst;
  if (row < 8192) {
    src = im + (size_t)row * 512;
    dst = nim + row;
  } else {
    src = s + (size_t)(row - 8192) * 512;
    dst = ns + (row - 8192);
  }
  float acc = 0.f;
#pragma unroll
  for (int i = 0; i < 8; i++) {
    float v = src[lane + 64 * i];
    acc = fmaf(v, v, acc);
  }
#pragma unroll
  for (int o = 32; o; o >>= 1) acc += __shfl_down(acc, o);
  if (lane == 0) *dst = sqrtf(acc);
}

// ---------------------------------------------------------------------------
// Kernel 2: fused per-pair attention + cosine similarity.
// One block per (c,q) pair. LS = context length, LQ = query length.
// i2t: ctx=images (LS=64), qry=captions (LQ=32)  -> sim[c_img*128+q_cap]
// t2i: ctx=captions (LS=32), qry=images (LQ=64)  -> sim[c_cap*128+q_img]
// ---------------------------------------------------------------------------
template <int LS, int LQ>
__global__ __launch_bounds__(256) void attn_dir(
    const float* __restrict__ ctx, const float* __restrict__ qry,
    const float* __restrict__ ctxN, const float* __restrict__ qryN,
    const float* __restrict__ cmask, const float* __restrict__ qmask,
    float* __restrict__ sim) {
  constexpr int D = 512, DC = 128, NCH = D / DC, STR = DC + 4;  // 132
  constexpr int SST = LQ + 1;
  constexpr int AST = LS + 1;
  const int q = blockIdx.x, c = blockIdx.y, t = threadIdx.x;

  // LDS layout (aliased):
  //   [0, LS*STR)              sA : staged context chunk  (aliases S)
  //   [LS*STR, (LS+LQ)*STR)    sB : staged query chunk
  //   [0, LS*SST)              S  : score matrix (alive only between GEMM and softmax)
  //   then A, rinvS, cinv, qinv, cmrow, cosv
  __shared__ float smem[(LS + LQ) * STR + LQ * AST + LS + LS + LQ + LS + LQ];
  float* sA = smem;
  float* sB = smem + LS * STR;
  float* Sb = smem;  // alias over sA (S fits: LS*SST <= LS*STR)
  float* Ab = smem + (LS + LQ) * STR;
  float* rinvS = Ab + LQ * AST;
  float* cinv = rinvS + LS;
  float* qinv = cinv + LS;
  float* cmrow = qinv + LQ;
  float* cosv = cmrow + LS;

  if (t < LS) {
    float n = ctxN[c * LS + t];
    cinv[t] = 1.0f / (n + EPSF);
    cmrow[t] = cmask[c * LS + t];
  }
  if (t < LQ) {
    float n = qryN[q * LQ + t];
    qinv[t] = 1.0f / (n + EPSF);
  }

  const float* ctxBase = ctx + (size_t)c * LS * D;
  const float* qryBase = qry + (size_t)q * LQ * D;

  // ---- Step A: S[s][l] = dot(ctx_norm[s], qry_norm[l]) ----
  constexpr int LH = LQ / 2;      // 16 (i2t) / 32 (t2i)
  constexpr int SGN = 256 / LH;   // 16 / 8
  constexpr int NSI = LS / SGN;   // 4 / 4
  const int lg = t % LH, sg = t / LH;
  float acc[NSI][2];
#pragma unroll
  for (int i = 0; i < NSI; i++) acc[i][0] = acc[i][1] = 0.f;

  for (int ch = 0; ch < NCH; ch++) {
    __syncthreads();  // protect prev reads (and preload on first iter)
    for (int idx = t; idx < LS * 32; idx += 256) {
      int row = idx >> 5, c4 = idx & 31;
      float4 v = *(const float4*)(ctxBase + row * D + ch * DC + c4 * 4);
      float scv = cinv[row];
      *(float4*)&sA[row * STR + c4 * 4] =
          make_float4(v.x * scv, v.y * scv, v.z * scv, v.w * scv);
    }
    for (int idx = t; idx < LQ * 32; idx += 256) {
      int row = idx >> 5, c4 = idx & 31;
      float4 v = *(const float4*)(qryBase + row * D + ch * DC + c4 * 4);
      float scv = qinv[row];
      *(float4*)&sB[row * STR + c4 * 4] =
          make_float4(v.x * scv, v.y * scv, v.z * scv, v.w * scv);
    }
    __syncthreads();
#pragma unroll 2
    for (int kk = 0; kk < DC; kk++) {
      float b0 = sB[lg * STR + kk];
      float b1 = sB[(lg + LH) * STR + kk];
#pragma unroll
      for (int i = 0; i < NSI; i++) {
        float a = sA[(sg + SGN * i) * STR + kk];
        acc[i][0] = fmaf(a, b0, acc[i][0]);
        acc[i][1] = fmaf(a, b1, acc[i][1]);
      }
    }
  }
  __syncthreads();
  // LeakyReLU(0.1) and write S (S aliases sA region; GEMM reads are done)
#pragma unroll
  for (int i = 0; i < NSI; i++) {
    int s = sg + SGN * i;
    float v0 = acc[i][0], v1 = acc[i][1];
    Sb[s * SST + lg] = v0 > 0.f ? v0 : 0.1f * v0;
    Sb[s * SST + lg + LH] = v1 > 0.f ? v1 : 0.1f * v1;
  }
  __syncthreads();

  // ---- Step B: l2norm over l for each s ----
  if (t < LS) {
    float sum = 0.f;
#pragma unroll 8
    for (int l = 0; l < LQ; l++) {
      float v = Sb[t * SST + l];
      sum = fmaf(v, v, sum);
    }
    rinvS[t] = 1.0f / (sqrtf(sum) + EPSF);
  }
  __syncthreads();

  // ---- Step C: softmax over s per l (with masks, lambda=20) ----
  if (t < LQ) {
    const int l = t;
    float qm = qmask[q * LQ + l];
    float m = -1e30f;
    for (int s = 0; s < LS; s++) {
      float v = LAM * (fmaf(Sb[s * SST + l], rinvS[s], qm + cmrow[s]));
      m = fmaxf(m, v);
    }
    float sum = 0.f;
    for (int s = 0; s < LS; s++) {
      float v = LAM * (fmaf(Sb[s * SST + l], rinvS[s], qm + cmrow[s]));
      float e = __expf(v - m);
      Ab[l * AST + s] = e;
      sum += e;
    }
    float r = 1.0f / sum;
    for (int s = 0; s < LS; s++) Ab[l * AST + s] *= r;
  }
  __syncthreads();

  // ---- Step D: wei[l,:] = A[l,:] @ ctx_norm; cos(qry_raw[l], wei[l]) ----
  constexpr int TPQ = 256 / LQ;      // 8 (i2t) / 4 (t2i)
  constexpr int FPT = DC / TPQ;      // floats per thread per chunk: 16 / 32
  constexpr int KPT = FPT / 4;       // float4s: 4 / 8
  const int l = t / TPQ, j = t % TPQ;
  float w12 = 0.f, wn2 = 0.f;

  for (int ch = 0; ch < NCH; ch++) {
    __syncthreads();  // S region dead; safe to overwrite sA/sB
    for (int idx = t; idx < LS * 32; idx += 256) {
      int row = idx >> 5, c4 = idx & 31;
      float4 v = *(const float4*)(ctxBase + row * D + ch * DC + c4 * 4);
      float scv = cinv[row];
      *(float4*)&sA[row * STR + c4 * 4] =
          make_float4(v.x * scv, v.y * scv, v.z * scv, v.w * scv);
    }
    for (int idx = t; idx < LQ * 32; idx += 256) {
      int row = idx >> 5, c4 = idx & 31;
      float4 v = *(const float4*)(qryBase + row * D + ch * DC + c4 * 4);
      *(float4*)&sB[row * STR + c4 * 4] = v;  // RAW query
    }
    __syncthreads();

    float wei[FPT];
#pragma unroll
    for (int k = 0; k < FPT; k++) wei[k] = 0.f;
    for (int s = 0; s < LS; s++) {
      float a = Ab[l * AST + s];
      const float* pa = &sA[s * STR + j * FPT];
#pragma unroll
      for (int m4 = 0; m4 < KPT; m4++) {
        float4 v = *(const float4*)(pa + 4 * m4);
        wei[4 * m4 + 0] = fmaf(a, v.x, wei[4 * m4 + 0]);
        wei[4 * m4 + 1] = fmaf(a, v.y, wei[4 * m4 + 1]);
        wei[4 * m4 + 2] = fmaf(a, v.z, wei[4 * m4 + 2]);
        wei[4 * m4 + 3] = fmaf(a, v.w, wei[4 * m4 + 3]);
      }
    }
    const float* pb = &sB[l * STR + j * FPT];
#pragma unroll
    for (int k = 0; k < FPT; k++) {
      float qv = pb[k];
      w12 = fmaf(qv, wei[k], w12);
      wn2 = fmaf(wei[k], wei[k], wn2);
    }
  }
  // reduce across the TPQ contiguous lanes handling the same l
#pragma unroll
  for (int o = TPQ >> 1; o > 0; o >>= 1) {
    w12 += __shfl_xor(w12, o);
    wn2 += __shfl_xor(wn2, o);
  }
  if (j == 0) {
    float qn = qryN[q * LQ + l];  // raw ||query row||
    cosv[l] = w12 / fmaxf(qn * sqrtf(wn2), 1e-8f);
  }
  __syncthreads();
  if (t == 0) {
    float sacc = 0.f;
    for (int l2 = 0; l2 < LQ; l2++) sacc += cosv[l2];
    sim[c * 128 + q] = sacc / (float)LQ;
  }
}

// ---------------------------------------------------------------------------
// Kernel 3: per-row loss terms. Block i (128 threads) computes:
//   grow[i] = x_ii*20 - lse(row i of gsim*20)
//   gcol[i] = x_ii*20 - lse(col i of gsim*20)
//   lrow[i] = sum_j pred_j * (logit_j - lse - log(label+1e-6))
// ---------------------------------------------------------------------------
__global__ __launch_bounds__(128) void loss_rows(
    const float* __restrict__ gsim, const float* __restrict__ i2t,
    const float* __restrict__ t2i, float* __restrict__ grow,
    float* __restrict__ gcol, float* __restrict__ lrow) {
  const int i = blockIdx.x, j = threadIdx.x;
  const int B = 128;
  __shared__ float sh[2];

  auto bmax = [&](float v) -> float {
#pragma unroll
    for (int o = 32; o; o >>= 1) v = fmaxf(v, __shfl_down(v, o));
    if ((j & 63) == 0) sh[j >> 6] = v;
    __syncthreads();
    float r = fmaxf(sh[0], sh[1]);
    __syncthreads();
    return r;
  };
  auto bsum = [&](float v) -> float {
#pragma unroll
    for (int o = 32; o; o >>= 1) v += __shfl_down(v, o);
    if ((j & 63) == 0) sh[j >> 6] = v;
    __syncthreads();
    float r = sh[0] + sh[1];
    __syncthreads();
    return r;
  };

  float xr = gsim[i * B + j] * 20.f;
  float xc = gsim[j * B + i] * 20.f;
  float sc = (i2t[i * B + j] + t2i[j * B + i]) * LAM;

  float mr = bmax(xr);
  float sr = bsum(__expf(xr - mr));
  float lser = mr + logf(sr);
  float mc = bmax(xc);
  float scs = bsum(__expf(xc - mc));
  float lsec = mc + logf(scs);
  float ml = bmax(sc);
  float sl = bsum(__expf(sc - ml));
  float lsel = ml + logf(sl);

  float pred = __expf(sc - lsel);
  float logLab = (i == j) ? logf(1.0f + 1e-6f) : logf(1e-6f);
  float term = pred * (sc - lsel - logLab);
  float tsum = bsum(term);

  if (j == 0) {
    float d = gsim[i * B + i] * 20.f;
    grow[i] = d - lser;
    gcol[i] = d - lsec;
    lrow[i] = tsum;
  }
}

// ---------------------------------------------------------------------------
// Kernel 4: final reduction -> (loss, global_loss, local_loss)
// ---------------------------------------------------------------------------
__global__ __launch_bounds__(128) void loss_final(const float* __restrict__ grow,
                                                  const float* __restrict__ gcol,
                                                  const float* __restrict__ lrow,
                                                  float* __restrict__ out) {
  const int j = threadIdx.x;
  __shared__ float sh[2];
  auto bsum = [&](float v) -> float {
#pragma unroll
    for (int o = 32; o; o >>= 1) v += __shfl_down(v, o);
    if ((j & 63) == 0) sh[j >> 6] = v;
    __syncthreads();
    float r = sh[0] + sh[1];
    __syncthreads();
    return r;
  };
  float a = bsum(grow[j]);
  float b = bsum(gcol[j]);
  float c = bsum(lrow[j]);
  if (j == 0) {
    float g = -(a / 128.f) - (b / 128.f);
    float l = c / 128.f;
    out[0] = g + l;
    out[1] = g;
    out[2] = l;
  }
}

extern "C" void kernel_launch(void* const* d_in, const int* in_sizes, int n_in,
                              void* d_out, int out_size, void* d_ws,
                              size_t ws_size, hipStream_t stream) {
  const float* gsim = (const float*)d_in[0];   // (128,128)
  const float* im = (const float*)d_in[1];     // (128,64,512)
  const float* s = (const float*)d_in[2];      // (128,32,512)
  const float* im_m = (const float*)d_in[3];   // (128,64)
  // d_in[4] = local_s_l (int32) unused in the fast path
  const float* s_m = (const float*)d_in[5];    // (128,32)
  float* out = (float*)d_out;

  float* ws = (float*)d_ws;
  float* nim = ws;            // 8192
  float* ns = ws + 8192;      // 4096
  float* i2t = ws + 12288;    // 16384  i2t_sim[img*128+cap]
  float* t2i = ws + 28672;    // 16384  t2i_sim[cap*128+img]
  float* grow = ws + 45056;   // 128
  float* gcol = ws + 45184;   // 128
  float* lrow = ws + 45312;   // 128

  row_norms<<<dim3(3072), dim3(256), 0, stream>>>(im, s, nim, ns);
  // i2t: context=images(LS=64), query=captions(LQ=32)
  attn_dir<64, 32><<<dim3(128, 128), dim3(256), 0, stream>>>(
      im, s, nim, ns, im_m, s_m, i2t);
  // t2i: context=captions(LS=32), query=images(LQ=64)
  attn_dir<32, 64><<<dim3(128, 128), dim3(256), 0, stream>>>(
      s, im, ns, nim, s_m, im_m, t2i);
  loss_rows<<<dim3(128), dim3(128), 0, stream>>>(gsim, i2t, t2i, grow, gcol, lrow);
  loss_final<<<dim3(1), dim3(128), 0, stream>>>(grow, gcol, lrow, out);
}

// Round 2
// 772.689 us; speedup vs baseline: 6.0891x; 6.0891x over previous
//
#include <hip/hip_runtime.h>
#include <math.h>

#define EPSF 1e-8f
#define LAM 20.0f

typedef short short8 __attribute__((ext_vector_type(8)));
typedef float f32x4 __attribute__((ext_vector_type(4)));

__device__ __forceinline__ unsigned short f2bf(float x) {
  unsigned u = __float_as_uint(x);
  unsigned r = (u >> 16) & 1u;
  u += 0x7fffu + r;
  return (unsigned short)(u >> 16);
}

// ---------------------------------------------------------------------------
// Kernel 1: row norms + bf16 normalized copies.
// im: 8192 rows x 512 -> nim, imn(bf16). s: 4096 rows x 512 -> ns, sn(bf16).
// 4 rows per 256-thread block, one wave per row; lane owns 8 consecutive elems.
// ---------------------------------------------------------------------------
__global__ __launch_bounds__(256) void norm_convert(
    const float* __restrict__ im, const float* __restrict__ s,
    float* __restrict__ nim, float* __restrict__ ns,
    unsigned short* __restrict__ imn, unsigned short* __restrict__ sn) {
  int row = blockIdx.x * 4 + (threadIdx.x >> 6);
  int lane = threadIdx.x & 63;
  const float* src;
  unsigned short* dst;
  float* ndst;
  if (row < 8192) {
    src = im + ((size_t)row << 9);
    dst = imn + ((size_t)row << 9);
    ndst = nim + row;
  } else {
    int r = row - 8192;
    src = s + ((size_t)r << 9);
    dst = sn + ((size_t)r << 9);
    ndst = ns + r;
  }
  float4 v0 = ((const float4*)src)[lane * 2];
  float4 v1 = ((const float4*)src)[lane * 2 + 1];
  float ss = 0.f;
  ss = fmaf(v0.x, v0.x, ss); ss = fmaf(v0.y, v0.y, ss);
  ss = fmaf(v0.z, v0.z, ss); ss = fmaf(v0.w, v0.w, ss);
  ss = fmaf(v1.x, v1.x, ss); ss = fmaf(v1.y, v1.y, ss);
  ss = fmaf(v1.z, v1.z, ss); ss = fmaf(v1.w, v1.w, ss);
#pragma unroll
  for (int o = 32; o; o >>= 1) ss += __shfl_xor(ss, o);
  float n = sqrtf(ss);
  if (lane == 0) *ndst = n;
  float ci = 1.0f / (n + EPSF);
  union {
    unsigned short us[8];
    uint4 v;
  } p;
  p.us[0] = f2bf(v0.x * ci); p.us[1] = f2bf(v0.y * ci);
  p.us[2] = f2bf(v0.z * ci); p.us[3] = f2bf(v0.w * ci);
  p.us[4] = f2bf(v1.x * ci); p.us[5] = f2bf(v1.y * ci);
  p.us[6] = f2bf(v1.z * ci); p.us[7] = f2bf(v1.w * ci);
  ((uint4*)dst)[lane] = p.v;
}

// ---------------------------------------------------------------------------
// Kernel 2: per-c Gram matrices of normalized context rows (fp32 exact).
// G[c][i][j] = dot(raw_i, raw_j) / ((n_i+eps)(n_j+eps)).  One block per c.
// ---------------------------------------------------------------------------
template <int LS>
__global__ __launch_bounds__(256) void gram(const float* __restrict__ raw,
                                            const float* __restrict__ nrm,
                                            float* __restrict__ G) {
  constexpr int STR = 132;      // fp32 row stride (pad 4)
  constexpr int NG = 256 / LS;  // 4 (LS=64) / 8 (LS=32)
  constexpr int MM = LS / NG;   // 16 / 4
  __shared__ __align__(16) float S[LS * STR];
  const int c = blockIdx.x, t = threadIdx.x;
  const int si = t % LS, g = t / LS;
  float acc[MM];
#pragma unroll
  for (int m = 0; m < MM; m++) acc[m] = 0.f;
  const float* base = raw + ((size_t)c * LS << 9);
  for (int ch = 0; ch < 4; ch++) {
    __syncthreads();
    for (int idx = t; idx < LS * 32; idx += 256) {
      int row = idx >> 5, k4 = idx & 31;
      *(float4*)(S + row * STR + k4 * 4) =
          ((const float4*)(base + ((size_t)row << 9) + (ch << 7)))[k4];
    }
    __syncthreads();
    for (int k4 = 0; k4 < 32; k4++) {
      float4 x = *(const float4*)(S + si * STR + k4 * 4);
#pragma unroll
      for (int m = 0; m < MM; m++) {
        float4 y = *(const float4*)(S + (g + m * NG) * STR + k4 * 4);
        acc[m] = fmaf(x.x, y.x, acc[m]);
        acc[m] = fmaf(x.y, y.y, acc[m]);
        acc[m] = fmaf(x.z, y.z, acc[m]);
        acc[m] = fmaf(x.w, y.w, acc[m]);
      }
    }
  }
  float ci = 1.0f / (nrm[c * LS + si] + EPSF);
#pragma unroll
  for (int m = 0; m < MM; m++) {
    int sj = g + m * NG;
    float cj = 1.0f / (nrm[c * LS + sj] + EPSF);
    G[(size_t)c * LS * LS + si * LS + sj] = acc[m] * ci * cj;
  }
}

// ---------------------------------------------------------------------------
// Kernel 3: fused per-pair attention + cosine sim, MFMA scores + Gram trick.
//   S0 = ctxn @ qryn^T         (bf16 MFMA, fp32 acc; raw cosine scores)
//   attn = softmax over s of LAM*(lrelu(S0)*rinvS + cm)    (qm drops: shift-inv)
//   dot(q,wei) = (nq+eps) * sum_s attn*S0 ;  ||wei||^2 = attn . G . attn^T
// One block per (c,q). 4 waves.
// ---------------------------------------------------------------------------
template <int LS, int LQ>
__global__ __launch_bounds__(256) void attn_mfma(
    const unsigned short* __restrict__ ctxn,  // (128,LS,512) bf16
    const unsigned short* __restrict__ qryn,  // (128,LQ,512) bf16
    const float* __restrict__ Gg,             // (128,LS,LS)
    const float* __restrict__ qnrm,           // (128*LQ) raw query norms
    const float* __restrict__ cmask,          // (128,LS)
    float* __restrict__ sim) {
  constexpr int SST = LQ + 1;                  // S0 stride (floats)
  constexpr int GST = LS + 4;                  // G stride (floats, f4-friendly)
  constexpr int ATST = LS + 4;                 // attn stride
  constexpr int NS = LS / 16;
  constexpr int SBOFF = LS * 272;              // bytes: B staging after A
  constexpr int STAGE = (LS + LQ) * 272;       // 26112 both dirs
  constexpr int S0OFF = LS * GST * 4;          // S0 after G (aliases staging)
  constexpr int ATOFF = STAGE;
  constexpr int SMOFF = ATOFF + LQ * ATST * 4;
  __shared__ __align__(16) char sm[SMOFF + (2 * LS + LQ) * 4];

  float* Gf = (float*)(sm);
  float* S0f = (float*)(sm + S0OFF);
  float* attnF = (float*)(sm + ATOFF);
  float* rinvS = (float*)(sm + SMOFF);
  float* cmv = rinvS + LS;
  float* cosv = cmv + LS;

  const int q = blockIdx.x, c = blockIdx.y, t = threadIdx.x;
  const int lane = t & 63, w = t >> 6;
  const int m16 = lane & 15, grp = lane >> 4;
  const int sTile = w % NS, lBase = (w / NS) * 2;

  const unsigned short* ctxB = ctxn + ((size_t)c * LS << 9);
  const unsigned short* qryB = qryn + ((size_t)q * LQ << 9);

  f32x4 acc0 = {0.f, 0.f, 0.f, 0.f};
  f32x4 acc1 = {0.f, 0.f, 0.f, 0.f};

  const char* aPtr = sm + (sTile * 16 + m16) * 272 + grp * 16;
  const char* b0Ptr = sm + SBOFF + (lBase * 16 + m16) * 272 + grp * 16;
  const char* b1Ptr = b0Ptr + 16 * 272;

  // ---- Phase 1: MFMA score GEMM over K=512 in 4 chunks of 128 ----
  for (int ch = 0; ch < 4; ch++) {
    __syncthreads();
    for (int idx = t; idx < LS * 16; idx += 256) {
      int row = idx >> 4, u = idx & 15;
      *(uint4*)(sm + row * 272 + u * 16) =
          ((const uint4*)(ctxB + ((size_t)row << 9) + (ch << 7)))[u];
    }
    for (int idx = t; idx < LQ * 16; idx += 256) {
      int row = idx >> 4, u = idx & 15;
      *(uint4*)(sm + SBOFF + row * 272 + u * 16) =
          ((const uint4*)(qryB + ((size_t)row << 9) + (ch << 7)))[u];
    }
    __syncthreads();
#pragma unroll
    for (int kk = 0; kk < 4; kk++) {
      short8 av = *(const short8*)(aPtr + kk * 64);
      short8 b0 = *(const short8*)(b0Ptr + kk * 64);
      short8 b1 = *(const short8*)(b1Ptr + kk * 64);
      acc0 = __builtin_amdgcn_mfma_f32_16x16x32_bf16(av, b0, acc0, 0, 0, 0);
      acc1 = __builtin_amdgcn_mfma_f32_16x16x32_bf16(av, b1, acc1, 0, 0, 0);
    }
  }
  __syncthreads();
  // write raw scores S0 (C/D layout: col=lane&15, row=(lane>>4)*4+reg)
  {
    int s0 = sTile * 16 + grp * 4;
    int l0 = lBase * 16 + m16, l1 = l0 + 16;
#pragma unroll
    for (int r = 0; r < 4; r++) {
      S0f[(s0 + r) * SST + l0] = acc0[r];
      S0f[(s0 + r) * SST + l1] = acc1[r];
    }
  }
  // stage G (aliases dead staging region, disjoint from S0) + context mask
  for (int idx = t; idx < LS * (LS / 4); idx += 256) {
    int row = idx / (LS / 4), k4 = idx % (LS / 4);
    *(float4*)(Gf + row * GST + k4 * 4) =
        ((const float4*)(Gg + (size_t)c * LS * LS + row * LS))[k4];
  }
  if (t < LS) cmv[t] = cmask[c * LS + t];
  __syncthreads();

  // ---- Phase 2a: rinvS[s] = 1/(||lrelu(S0[s,:])||_2 + eps) ----
  {
    constexpr int JP = 256 / LS;
    int s = t / JP, j = t % JP;
    float ss = 0.f;
#pragma unroll
    for (int m = 0; m < LQ / JP; m++) {
      float v = S0f[s * SST + (j + m * JP)];
      v = v > 0.f ? v : 0.1f * v;
      ss = fmaf(v, v, ss);
    }
#pragma unroll
    for (int o = JP / 2; o; o >>= 1) ss += __shfl_xor(ss, o);
    if (j == 0) rinvS[s] = 1.0f / (sqrtf(ss) + EPSF);
  }
  __syncthreads();

  // ---- Phase 2b: softmax over s for each l (TPQ lanes per l) ----
  constexpr int TPQ = 256 / LQ;   // 8 (i2t) / 4 (t2i)
  constexpr int NSUB = LS / TPQ;  // 8 both
  const int l = t / TPQ, j = t % TPQ;
  float ev[NSUB];
  float mx = -1e30f;
#pragma unroll
  for (int m = 0; m < NSUB; m++) {
    int s = j + m * TPQ;
    float v = S0f[s * SST + l];
    v = v > 0.f ? v : 0.1f * v;
    v = LAM * fmaf(v, rinvS[s], cmv[s]);
    ev[m] = v;
    mx = fmaxf(mx, v);
  }
#pragma unroll
  for (int o = TPQ / 2; o; o >>= 1) mx = fmaxf(mx, __shfl_xor(mx, o));
  float smv = 0.f;
#pragma unroll
  for (int m = 0; m < NSUB; m++) {
    float e = __expf(ev[m] - mx);
    ev[m] = e;
    smv += e;
  }
#pragma unroll
  for (int o = TPQ / 2; o; o >>= 1) smv += __shfl_xor(smv, o);
  float inv = 1.0f / smv;
#pragma unroll
  for (int m = 0; m < NSUB; m++) {
    ev[m] *= inv;
    attnF[l * ATST + (j + m * TPQ)] = ev[m];
  }
  __syncthreads();

  // ---- Phase 3: w12 = sum_s a_s S0[s][l]; wn2 = a . G . a^T ----
  float w12 = 0.f, wn2 = 0.f;
#pragma unroll
  for (int m = 0; m < NSUB; m++) {
    int sp = j + m * TPQ;
    w12 = fmaf(ev[m], S0f[sp * SST + l], w12);
    float ux = 0.f, uy = 0.f, uz = 0.f, uw = 0.f;
    const float4* gr = (const float4*)(Gf + sp * GST);
    const float4* ar = (const float4*)(attnF + l * ATST);
#pragma unroll 4
    for (int k4 = 0; k4 < LS / 4; k4++) {
      float4 gv = gr[k4], av = ar[k4];
      ux = fmaf(gv.x, av.x, ux);
      uy = fmaf(gv.y, av.y, uy);
      uz = fmaf(gv.z, av.z, uz);
      uw = fmaf(gv.w, av.w, uw);
    }
    wn2 = fmaf(ev[m], (ux + uy) + (uz + uw), wn2);
  }
#pragma unroll
  for (int o = TPQ / 2; o; o >>= 1) {
    w12 += __shfl_xor(w12, o);
    wn2 += __shfl_xor(wn2, o);
  }
  if (j == 0) {
    float nq = qnrm[q * LQ + l];
    float denom = fmaxf(nq * sqrtf(fmaxf(wn2, 0.f)), 1e-8f);
    cosv[l] = (nq + EPSF) * w12 / denom;
  }
  __syncthreads();
  if (t == 0) {
    float sacc = 0.f;
    for (int l2 = 0; l2 < LQ; l2++) sacc += cosv[l2];
    sim[c * 128 + q] = sacc * (1.0f / (float)LQ);
  }
}

// ---------------------------------------------------------------------------
// Kernel 4: per-row loss terms (unchanged from R1, exact).
// ---------------------------------------------------------------------------
__global__ __launch_bounds__(128) void loss_rows(
    const float* __restrict__ gsim, const float* __restrict__ i2t,
    const float* __restrict__ t2i, float* __restrict__ grow,
    float* __restrict__ gcol, float* __restrict__ lrow) {
  const int i = blockIdx.x, j = threadIdx.x;
  const int B = 128;
  __shared__ float sh[2];

  auto bmax = [&](float v) -> float {
#pragma unroll
    for (int o = 32; o; o >>= 1) v = fmaxf(v, __shfl_down(v, o));
    if ((j & 63) == 0) sh[j >> 6] = v;
    __syncthreads();
    float r = fmaxf(sh[0], sh[1]);
    __syncthreads();
    return r;
  };
  auto bsum = [&](float v) -> float {
#pragma unroll
    for (int o = 32; o; o >>= 1) v += __shfl_down(v, o);
    if ((j & 63) == 0) sh[j >> 6] = v;
    __syncthreads();
    float r = sh[0] + sh[1];
    __syncthreads();
    return r;
  };

  float xr = gsim[i * B + j] * 20.f;
  float xc = gsim[j * B + i] * 20.f;
  float sc = (i2t[i * B + j] + t2i[j * B + i]) * LAM;

  float mr = bmax(xr);
  float sr = bsum(__expf(xr - mr));
  float lser = mr + logf(sr);
  float mc = bmax(xc);
  float scs = bsum(__expf(xc - mc));
  float lsec = mc + logf(scs);
  float ml = bmax(sc);
  float sl = bsum(__expf(sc - ml));
  float lsel = ml + logf(sl);

  float pred = __expf(sc - lsel);
  float logLab = (i == j) ? logf(1.0f + 1e-6f) : logf(1e-6f);
  float term = pred * (sc - lsel - logLab);
  float tsum = bsum(term);

  if (j == 0) {
    float d = gsim[i * B + i] * 20.f;
    grow[i] = d - lser;
    gcol[i] = d - lsec;
    lrow[i] = tsum;
  }
}

__global__ __launch_bounds__(128) void loss_final(const float* __restrict__ grow,
                                                  const float* __restrict__ gcol,
                                                  const float* __restrict__ lrow,
                                                  float* __restrict__ out) {
  const int j = threadIdx.x;
  __shared__ float sh[2];
  auto bsum = [&](float v) -> float {
#pragma unroll
    for (int o = 32; o; o >>= 1) v += __shfl_down(v, o);
    if ((j & 63) == 0) sh[j >> 6] = v;
    __syncthreads();
    float r = sh[0] + sh[1];
    __syncthreads();
    return r;
  };
  float a = bsum(grow[j]);
  float b = bsum(gcol[j]);
  float c = bsum(lrow[j]);
  if (j == 0) {
    float g = -(a / 128.f) - (b / 128.f);
    float l = c / 128.f;
    out[0] = g + l;
    out[1] = g;
    out[2] = l;
  }
}

extern "C" void kernel_launch(void* const* d_in, const int* in_sizes, int n_in,
                              void* d_out, int out_size, void* d_ws,
                              size_t ws_size, hipStream_t stream) {
  const float* gsim = (const float*)d_in[0];  // (128,128)
  const float* im = (const float*)d_in[1];    // (128,64,512)
  const float* s = (const float*)d_in[2];     // (128,32,512)
  const float* im_m = (const float*)d_in[3];  // (128,64)
  const float* s_m = (const float*)d_in[5];   // (128,32)
  float* out = (float*)d_out;

  float* ws = (float*)d_ws;
  float* nim = ws;                       // 8192
  float* ns = ws + 8192;                 // 4096
  float* i2t = ws + 12288;               // 16384
  float* t2i = ws + 28672;               // 16384
  float* grow = ws + 45056;              // 128
  float* gcol = ws + 45184;              // 128
  float* lrow = ws + 45312;              // 128
  float* Gim = ws + 45568;               // 128*64*64 = 524288
  float* Gs = ws + 569856;               // 128*32*32 = 131072
  unsigned short* imn = (unsigned short*)(ws + 700928);   // 128*64*512 bf16
  unsigned short* sn = (unsigned short*)(ws + 2798080);   // 128*32*512 bf16
  // total ws use: (2798080 + 1048576) floats-equiv = ~13.3 MB

  norm_convert<<<dim3(3072), dim3(256), 0, stream>>>(im, s, nim, ns, imn, sn);
  gram<64><<<dim3(128), dim3(256), 0, stream>>>(im, nim, Gim);
  gram<32><<<dim3(128), dim3(256), 0, stream>>>(s, ns, Gs);
  // i2t: ctx=images(LS=64), qry=captions(LQ=32)
  attn_mfma<64, 32><<<dim3(128, 128), dim3(256), 0, stream>>>(
      imn, sn, Gim, ns, im_m, i2t);
  // t2i: ctx=captions(LS=32), qry=images(LQ=64)
  attn_mfma<32, 64><<<dim3(128, 128), dim3(256), 0, stream>>>(
      sn, imn, Gs, nim, s_m, t2i);
  loss_rows<<<dim3(128), dim3(128), 0, stream>>>(gsim, i2t, t2i, grow, gcol,
                                                 lrow);
  loss_final<<<dim3(1), dim3(128), 0, stream>>>(grow, gcol, lrow, out);
}

// Round 3
// 395.927 us; speedup vs baseline: 11.8835x; 1.9516x over previous
//
#include <hip/hip_runtime.h>
#include <math.h>

#define EPSF 1e-8f
#define LAM 20.0f

typedef short short8 __attribute__((ext_vector_type(8)));
typedef float f32x4 __attribute__((ext_vector_type(4)));

__device__ __forceinline__ unsigned short f2bf(float x) {
  unsigned u = __float_as_uint(x);
  u += 0x7fffu + ((u >> 16) & 1u);
  return (unsigned short)(u >> 16);
}
__device__ __forceinline__ float bf2f(unsigned short h) {
  return __uint_as_float(((unsigned)h) << 16);
}

// ---------------------------------------------------------------------------
// Kernel 1: row norms + bf16 normalized copies (unchanged from R2).
// ---------------------------------------------------------------------------
__global__ __launch_bounds__(256) void norm_convert(
    const float* __restrict__ im, const float* __restrict__ s,
    float* __restrict__ nim, float* __restrict__ ns,
    unsigned short* __restrict__ imn, unsigned short* __restrict__ sn) {
  int row = blockIdx.x * 4 + (threadIdx.x >> 6);
  int lane = threadIdx.x & 63;
  const float* src;
  unsigned short* dst;
  float* ndst;
  if (row < 8192) {
    src = im + ((size_t)row << 9);
    dst = imn + ((size_t)row << 9);
    ndst = nim + row;
  } else {
    int r = row - 8192;
    src = s + ((size_t)r << 9);
    dst = sn + ((size_t)r << 9);
    ndst = ns + r;
  }
  float4 v0 = ((const float4*)src)[lane * 2];
  float4 v1 = ((const float4*)src)[lane * 2 + 1];
  float ss = 0.f;
  ss = fmaf(v0.x, v0.x, ss); ss = fmaf(v0.y, v0.y, ss);
  ss = fmaf(v0.z, v0.z, ss); ss = fmaf(v0.w, v0.w, ss);
  ss = fmaf(v1.x, v1.x, ss); ss = fmaf(v1.y, v1.y, ss);
  ss = fmaf(v1.z, v1.z, ss); ss = fmaf(v1.w, v1.w, ss);
#pragma unroll
  for (int o = 32; o; o >>= 1) ss += __shfl_xor(ss, o);
  float n = sqrtf(ss);
  if (lane == 0) *ndst = n;
  float ci = 1.0f / (n + EPSF);
  union { unsigned short us[8]; uint4 v; } p;
  p.us[0] = f2bf(v0.x * ci); p.us[1] = f2bf(v0.y * ci);
  p.us[2] = f2bf(v0.z * ci); p.us[3] = f2bf(v0.w * ci);
  p.us[4] = f2bf(v1.x * ci); p.us[5] = f2bf(v1.y * ci);
  p.us[6] = f2bf(v1.z * ci); p.us[7] = f2bf(v1.w * ci);
  ((uint4*)dst)[lane] = p.v;
}

// ---------------------------------------------------------------------------
// Kernel 2: bf16 Gram matrices via MFMA. One block per c. G = ctxn @ ctxn^T.
// ---------------------------------------------------------------------------
template <int LS>
__global__ __launch_bounds__(256, 2) void gram_mfma(
    const unsigned short* __restrict__ ctxn, unsigned short* __restrict__ Gbf) {
  constexpr int T = LS / 16, RW = T / 2;  // 4,2 (LS=64) / 2,1 (LS=32)
  __shared__ __align__(16) char sm[LS * 272];
  const int c = blockIdx.x, t = threadIdx.x;
  const int w = t >> 6, lane = t & 63, m16 = lane & 15, grp = lane >> 4;
  const int rT0 = (w & 1) * RW, cT0 = (w >> 1) * RW;
  const unsigned short* base = ctxn + ((size_t)c * LS << 9);
  f32x4 g[RW][RW];
#pragma unroll
  for (int ri = 0; ri < RW; ri++)
#pragma unroll
    for (int ci = 0; ci < RW; ci++) g[ri][ci] = {0.f, 0.f, 0.f, 0.f};

  for (int ch = 0; ch < 4; ch++) {
    __syncthreads();
    for (int idx = t; idx < LS * 16; idx += 256) {
      int row = idx >> 4, u = idx & 15;
      *(uint4*)(sm + row * 272 + u * 16) =
          ((const uint4*)(base + ((size_t)row << 9) + (ch << 7)))[u];
    }
    __syncthreads();
#pragma unroll
    for (int kk = 0; kk < 4; kk++) {
      short8 a[RW], b[RW];
#pragma unroll
      for (int ri = 0; ri < RW; ri++)
        a[ri] = *(const short8*)(sm + ((rT0 + ri) * 16 + m16) * 272 + kk * 64 + grp * 16);
#pragma unroll
      for (int ci = 0; ci < RW; ci++)
        b[ci] = *(const short8*)(sm + ((cT0 + ci) * 16 + m16) * 272 + kk * 64 + grp * 16);
#pragma unroll
      for (int ri = 0; ri < RW; ri++)
#pragma unroll
        for (int ci = 0; ci < RW; ci++)
          g[ri][ci] = __builtin_amdgcn_mfma_f32_16x16x32_bf16(a[ri], b[ci], g[ri][ci], 0, 0, 0);
    }
  }
#pragma unroll
  for (int ri = 0; ri < RW; ri++)
#pragma unroll
    for (int ci = 0; ci < RW; ci++)
#pragma unroll
      for (int r = 0; r < 4; r++) {
        int s = (rT0 + ri) * 16 + grp * 4 + r;
        int sp = (cT0 + ci) * 16 + m16;
        Gbf[(size_t)c * LS * LS + s * LS + sp] = f2bf(g[ri][ci][r]);
      }
}

// ---------------------------------------------------------------------------
// Kernel 3: q-grouped fused attention. Block = (q-group g, c). N = GQ*LQ = 128.
//   Phase 1: S0(LS x N) = ctxn @ qryn^T  (bf16 MFMA, 2x4-tile waves)
//   Phase 2: rinvS per (pair,s); softmax per column n (2 lanes/col); w12.
//   Phase 3: U = attn @ G via MFMA (bf16); wn2 from C-layout regs; cos; sim.
// ---------------------------------------------------------------------------
template <int LS, int LQ, int GQ>
__global__ __launch_bounds__(256, (GQ == 4) ? 2 : 3) void attn_group(
    const unsigned short* __restrict__ ctxn,  // (128,LS,512) bf16
    const unsigned short* __restrict__ qryn,  // (128,LQ,512) bf16
    const unsigned short* __restrict__ Gbf,   // (128,LS,LS) bf16
    const float* __restrict__ qnrm,           // (128*LQ) raw query norms
    const float* __restrict__ cmask,          // (128,LS)
    float* __restrict__ sim) {
  constexpr int N = GQ * LQ;  // 128
  static_assert(N == 128, "N must be 128");
  constexpr int SBOFF = LS * 272;            // B staging after A (bytes)
  constexpr int SEND = (LS + N) * 272;       // staging region size
  constexpr int NST = 131;                   // S0 float stride (odd: no conflicts)
  constexpr int ATOFF = LS * NST * 4;        // attn bf16 after S0 (both alias staging)
  constexpr int ATB = LS * 2 + 16;           // attn row bytes (16B aligned)
  constexpr int GOFF = SEND;                 // G bf16 region
  constexpr int GSB = LS * 2 + 16;
  constexpr int FOFF = GOFF + LS * GSB;      // float scratch region
  constexpr int SMEM = FOFF + (N + GQ * LS + LS + 4) * 4;
  static_assert(ATOFF + N * ATB <= SEND, "attn overflows staging alias");
  static_assert(SMEM <= 65536, "LDS overflow");
  __shared__ __align__(16) char sm[SMEM];

  float* S0f = (float*)sm;
  float* w12v = (float*)(sm + FOFF);
  float* rinv = w12v + N;
  float* cmv = rinv + GQ * LS;
  float* psum = cmv + LS;

  const int g = blockIdx.x, c = blockIdx.y, t = threadIdx.x;
  const int q0 = g * GQ;
  const int w = t >> 6, lane = t & 63, m16 = lane & 15, grp = lane >> 4;

  const unsigned short* ctxB = ctxn + ((size_t)c * LS << 9);
  const unsigned short* qryB = qryn + ((size_t)q0 * LQ << 9);

  // ---- Phase 1: score GEMM, wave tile = SW s-tiles x 4 n-tiles ----
  constexpr int SW = LS / 32;  // 2 (i2t) / 1 (t2i)
  const int sT0 = (w & 1) * SW, nT0 = (w >> 1) * 4;
  f32x4 acc[SW][4];
#pragma unroll
  for (int si = 0; si < SW; si++)
#pragma unroll
    for (int ni = 0; ni < 4; ni++) acc[si][ni] = {0.f, 0.f, 0.f, 0.f};

  for (int ch = 0; ch < 4; ch++) {
    __syncthreads();
    for (int idx = t; idx < LS * 16; idx += 256) {
      int row = idx >> 4, u = idx & 15;
      *(uint4*)(sm + row * 272 + u * 16) =
          ((const uint4*)(ctxB + ((size_t)row << 9) + (ch << 7)))[u];
    }
    for (int idx = t; idx < N * 16; idx += 256) {
      int row = idx >> 4, u = idx & 15;
      *(uint4*)(sm + SBOFF + row * 272 + u * 16) =
          ((const uint4*)(qryB + ((size_t)row << 9) + (ch << 7)))[u];
    }
    __syncthreads();
#pragma unroll
    for (int kk = 0; kk < 4; kk++) {
      short8 av[SW], bv[4];
#pragma unroll
      for (int si = 0; si < SW; si++)
        av[si] = *(const short8*)(sm + ((sT0 + si) * 16 + m16) * 272 + kk * 64 + grp * 16);
#pragma unroll
      for (int ni = 0; ni < 4; ni++)
        bv[ni] = *(const short8*)(sm + SBOFF + ((nT0 + ni) * 16 + m16) * 272 + kk * 64 + grp * 16);
#pragma unroll
      for (int si = 0; si < SW; si++)
#pragma unroll
        for (int ni = 0; ni < 4; ni++)
          acc[si][ni] = __builtin_amdgcn_mfma_f32_16x16x32_bf16(av[si], bv[ni], acc[si][ni], 0, 0, 0);
    }
  }
  __syncthreads();  // staging dead; S0/attn alias it from here on
  // write S0 (C/D layout: row s = grp*4+r, col n = m16 within tile)
#pragma unroll
  for (int si = 0; si < SW; si++)
#pragma unroll
    for (int ni = 0; ni < 4; ni++) {
      int sb = (sT0 + si) * 16 + grp * 4;
      int n = (nT0 + ni) * 16 + m16;
#pragma unroll
      for (int r = 0; r < 4; r++) S0f[(sb + r) * NST + n] = acc[si][ni][r];
    }
  // stage G (separate region) + context mask
  for (int idx = t; idx < LS * LS / 8; idx += 256) {
    int row = idx / (LS / 8), u = idx % (LS / 8);
    *(uint4*)(sm + GOFF + row * GSB + u * 16) =
        ((const uint4*)(Gbf + (size_t)c * LS * LS + row * LS))[u];
  }
  if (t < LS) cmv[t] = cmask[c * LS + t];
  __syncthreads();

  // ---- Phase 2a: rinv[p*LS+s] over the pair's LQ columns ----
  if (t < GQ * LS) {
    int p = t / LS, s = t % LS;
    const float* base2 = S0f + s * NST + p * LQ;
    float ss = 0.f;
#pragma unroll 8
    for (int l = 0; l < LQ; l++) {
      float v = base2[l];
      v = v > 0.f ? v : 0.1f * v;
      ss = fmaf(v, v, ss);
    }
    rinv[t] = 1.0f / (sqrtf(ss) + EPSF);
  }
  __syncthreads();

  // ---- Phase 2b: softmax per column n (2 lanes per column) + w12 ----
  {
    constexpr int NS2 = LS / 2;
    const int n = t >> 1, j = t & 1;
    const int p = n / LQ;
    float ev[NS2];
    float mx = -1e30f;
#pragma unroll
    for (int m = 0; m < NS2; m++) {
      int s = j + 2 * m;
      float v = S0f[s * NST + n];
      v = v > 0.f ? v : 0.1f * v;
      v = LAM * fmaf(v, rinv[p * LS + s], cmv[s]);
      ev[m] = v;
      mx = fmaxf(mx, v);
    }
    mx = fmaxf(mx, __shfl_xor(mx, 1));
    float sum = 0.f;
#pragma unroll
    for (int m = 0; m < NS2; m++) {
      float e = __expf(ev[m] - mx);
      ev[m] = e;
      sum += e;
    }
    sum += __shfl_xor(sum, 1);
    float inv = 1.0f / sum;
    float w12 = 0.f;
#pragma unroll
    for (int m = 0; m < NS2; m++) {
      int s = j + 2 * m;
      float a = ev[m] * inv;
      *(unsigned short*)(sm + ATOFF + n * ATB + s * 2) = f2bf(a);
      w12 = fmaf(a, S0f[s * NST + n], w12);
    }
    w12 += __shfl_xor(w12, 1);
    if (j == 0) w12v[n] = w12;
  }
  __syncthreads();

  // ---- Phase 3: U = attn @ G via MFMA; wn2 from C-layout regs; cos ----
  {
    constexpr int ST = LS / 16;  // s'-tiles: 4 / 2
    constexpr int KS = LS / 32;  // k-steps: 2 / 1
    const int p = (GQ == 4) ? w : (w & 1);
    const int lbt = (GQ == 4) ? 0 : (w >> 1) * 2;  // first l-tile (2 per wave)
    f32x4 u[2][ST];
#pragma unroll
    for (int li = 0; li < 2; li++)
#pragma unroll
      for (int st = 0; st < ST; st++) u[li][st] = {0.f, 0.f, 0.f, 0.f};
#pragma unroll
    for (int ks = 0; ks < KS; ks++) {
      short8 a[2], b[ST];
#pragma unroll
      for (int li = 0; li < 2; li++) {
        int n = p * LQ + (lbt + li) * 16 + m16;
        a[li] = *(const short8*)(sm + ATOFF + n * ATB + ks * 64 + grp * 16);
      }
#pragma unroll
      for (int st = 0; st < ST; st++)
        b[st] = *(const short8*)(sm + GOFF + (st * 16 + m16) * GSB + ks * 64 + grp * 16);
#pragma unroll
      for (int li = 0; li < 2; li++)
#pragma unroll
        for (int st = 0; st < ST; st++)
          u[li][st] = __builtin_amdgcn_mfma_f32_16x16x32_bf16(a[li], b[st], u[li][st], 0, 0, 0);
    }
    float wsum = 0.f;
#pragma unroll
    for (int li = 0; li < 2; li++)
#pragma unroll
      for (int r = 0; r < 4; r++) {
        int l = (lbt + li) * 16 + grp * 4 + r;
        int n = p * LQ + l;
        float v = 0.f;
#pragma unroll
        for (int st = 0; st < ST; st++) {
          float a = bf2f(*(const unsigned short*)(sm + ATOFF + n * ATB + (st * 16 + m16) * 2));
          v = fmaf(a, u[li][st][r], v);
        }
#pragma unroll
        for (int o = 1; o < 16; o <<= 1) v += __shfl_xor(v, o);
        if (m16 == 0) {
          float nq = qnrm[(q0 + p) * LQ + l];
          float w12 = w12v[n];
          float denom = fmaxf(nq * sqrtf(fmaxf(v, 0.f)), 1e-8f);
          wsum += (nq + EPSF) * w12 / denom;
        }
      }
#pragma unroll
    for (int o = 16; o < 64; o <<= 1) wsum += __shfl_xor(wsum, o);
    if (lane == 0) psum[w] = wsum;
  }
  __syncthreads();
  if (t < GQ) {
    float tot = psum[t];
    if (GQ == 2) tot += psum[t + 2];
    sim[c * 128 + q0 + t] = tot * (1.0f / (float)LQ);
  }
}

// ---------------------------------------------------------------------------
// Kernel 4/5: loss reductions (unchanged, exact).
// ---------------------------------------------------------------------------
__global__ __launch_bounds__(128) void loss_rows(
    const float* __restrict__ gsim, const float* __restrict__ i2t,
    const float* __restrict__ t2i, float* __restrict__ grow,
    float* __restrict__ gcol, float* __restrict__ lrow) {
  const int i = blockIdx.x, j = threadIdx.x;
  const int B = 128;
  __shared__ float sh[2];
  auto bmax = [&](float v) -> float {
#pragma unroll
    for (int o = 32; o; o >>= 1) v = fmaxf(v, __shfl_down(v, o));
    if ((j & 63) == 0) sh[j >> 6] = v;
    __syncthreads();
    float r = fmaxf(sh[0], sh[1]);
    __syncthreads();
    return r;
  };
  auto bsum = [&](float v) -> float {
#pragma unroll
    for (int o = 32; o; o >>= 1) v += __shfl_down(v, o);
    if ((j & 63) == 0) sh[j >> 6] = v;
    __syncthreads();
    float r = sh[0] + sh[1];
    __syncthreads();
    return r;
  };
  float xr = gsim[i * B + j] * 20.f;
  float xc = gsim[j * B + i] * 20.f;
  float sc = (i2t[i * B + j] + t2i[j * B + i]) * LAM;
  float mr = bmax(xr);
  float lser = mr + logf(bsum(__expf(xr - mr)));
  float mc = bmax(xc);
  float lsec = mc + logf(bsum(__expf(xc - mc)));
  float ml = bmax(sc);
  float lsel = ml + logf(bsum(__expf(sc - ml)));
  float pred = __expf(sc - lsel);
  float logLab = (i == j) ? logf(1.0f + 1e-6f) : logf(1e-6f);
  float tsum = bsum(pred * (sc - lsel - logLab));
  if (j == 0) {
    float d = gsim[i * B + i] * 20.f;
    grow[i] = d - lser;
    gcol[i] = d - lsec;
    lrow[i] = tsum;
  }
}

__global__ __launch_bounds__(128) void loss_final(const float* __restrict__ grow,
                                                  const float* __restrict__ gcol,
                                                  const float* __restrict__ lrow,
                                                  float* __restrict__ out) {
  const int j = threadIdx.x;
  __shared__ float sh[2];
  auto bsum = [&](float v) -> float {
#pragma unroll
    for (int o = 32; o; o >>= 1) v += __shfl_down(v, o);
    if ((j & 63) == 0) sh[j >> 6] = v;
    __syncthreads();
    float r = sh[0] + sh[1];
    __syncthreads();
    return r;
  };
  float a = bsum(grow[j]);
  float b = bsum(gcol[j]);
  float c = bsum(lrow[j]);
  if (j == 0) {
    float gl = -(a / 128.f) - (b / 128.f);
    float ll = c / 128.f;
    out[0] = gl + ll;
    out[1] = gl;
    out[2] = ll;
  }
}

extern "C" void kernel_launch(void* const* d_in, const int* in_sizes, int n_in,
                              void* d_out, int out_size, void* d_ws,
                              size_t ws_size, hipStream_t stream) {
  const float* gsim = (const float*)d_in[0];  // (128,128)
  const float* im = (const float*)d_in[1];    // (128,64,512)
  const float* s = (const float*)d_in[2];     // (128,32,512)
  const float* im_m = (const float*)d_in[3];  // (128,64)
  const float* s_m = (const float*)d_in[5];   // (128,32)
  float* out = (float*)d_out;

  float* ws = (float*)d_ws;
  float* nim = ws;                                         // 8192
  float* ns = ws + 8192;                                   // 4096
  float* i2t = ws + 12288;                                 // 16384
  float* t2i = ws + 28672;                                 // 16384
  float* grow = ws + 45056;                                // 128
  float* gcol = ws + 45184;                                // 128
  float* lrow = ws + 45312;                                // 128
  unsigned short* Gim = (unsigned short*)(ws + 45440);     // 128*64*64 bf16
  unsigned short* Gs = (unsigned short*)(ws + 307584);     // 128*32*32 bf16
  unsigned short* imn = (unsigned short*)(ws + 373120);    // 128*64*512 bf16
  unsigned short* sn = (unsigned short*)(ws + 2470272);    // 128*32*512 bf16

  norm_convert<<<dim3(3072), dim3(256), 0, stream>>>(im, s, nim, ns, imn, sn);
  gram_mfma<64><<<dim3(128), dim3(256), 0, stream>>>(imn, Gim);
  gram_mfma<32><<<dim3(128), dim3(256), 0, stream>>>(sn, Gs);
  // i2t: ctx=images(LS=64), qry=captions(LQ=32), GQ=4 -> 32 groups
  attn_group<64, 32, 4><<<dim3(32, 128), dim3(256), 0, stream>>>(
      imn, sn, Gim, ns, im_m, i2t);
  // t2i: ctx=captions(LS=32), qry=images(LQ=64), GQ=2 -> 64 groups
  attn_group<32, 64, 2><<<dim3(64, 128), dim3(256), 0, stream>>>(
      sn, imn, Gs, nim, s_m, t2i);
  loss_rows<<<dim3(128), dim3(128), 0, stream>>>(gsim, i2t, t2i, grow, gcol, lrow);
  loss_final<<<dim3(1), dim3(128), 0, stream>>>(grow, gcol, lrow, out);
}